// Round 1
// baseline (3004.234 us; speedup 1.0000x reference)
//
#include <hip/hip_runtime.h>
#include <hip/hip_bf16.h>
#include <math.h>

#define BNROWS (4096*32)   // 131072
#define HDIM   256
#define K0DIM  80
#define DOBS   64
#define DACT   16
#define RB     32          // rows per MLP block

// ---------------------------------------------------------------------------
// one-time (per launch) transpose of w2 [256x256] -> w2t so the backward GEMM
// reads contiguous weight vectors.
__global__ void transpose_w2_kernel(const float* __restrict__ w2,
                                    float* __restrict__ w2t) {
    int id = blockIdx.x * 256 + threadIdx.x;      // 65536 total
    int k = id >> 8, n = id & 255;
    w2t[n * 256 + k] = w2[(size_t)k * 256 + n];
}

// ---------------------------------------------------------------------------
// Fused critic forward + VJP wrt actions.
//   q[r]       = w3 . relu(w2^T relu(w1^T h0 + b1) + b2) + b3
//   score[r,:] = d q / d a   (last 16 columns of input)
// 32 rows per block, 256 threads. All activations stored transposed [k][r]
// in LDS so the GEMM inner loop is ds_read_b128 (4 rows) + global dwordx4
// (4 cols) + 16 v_fmac.
__global__ __launch_bounds__(256) void mlp_kernel(
    const float* __restrict__ obs,   // [BN,64]
    const float* __restrict__ a_in,  // [BN,16]
    const float* __restrict__ w1,    // [80,256]
    const float* __restrict__ b1,    // [256]
    const float* __restrict__ w2,    // [256,256]
    const float* __restrict__ b2,    // [256]
    const float* __restrict__ w3,    // [256]
    const float* __restrict__ b3,    // [1]
    const float* __restrict__ w2t,   // [256,256] (w2 transposed)
    float* __restrict__ score,       // [BN,16]
    float* __restrict__ qout)        // [BN]
{
    __shared__ float h0t[K0DIM * RB];   // [k][r], k<80
    __shared__ float h1t[HDIM * RB];    // [n][r]  (later reused as dz1T)
    __shared__ float gt[HDIM * RB];     // dz2T [n][r]
    __shared__ float qs[RB];

    const int tid  = threadIdx.x;
    const int row0 = blockIdx.x * RB;

    // ---- Phase A: stage h0 = [obs | a], transposed
    for (int idx = tid; idx < K0DIM * RB; idx += 256) {
        int k = idx >> 5, r = idx & 31;
        float v;
        if (k < DOBS) v = obs[(size_t)(row0 + r) * DOBS + k];
        else          v = a_in[(size_t)(row0 + r) * DACT + (k - DOBS)];
        h0t[idx] = v;                   // idx == k*32 + r
    }
    if (tid < RB) qs[tid] = 0.f;
    __syncthreads();

    const int lane = tid & 63;
    const int wv   = tid >> 6;
    const int r4   = (lane & 7) * 4;            // row-tile base (0..28)
    const int ct   = (lane >> 3) + (wv << 3);   // col-tile id in [0,32)

    // ---- Phase B: z1 = h0 @ w1 + b1, relu -> h1t
    for (int it = 0; it < 2; ++it) {
        const int n4 = 4 * (ct + 32 * it);
        float acc[4][4];                        // [col][row]
        #pragma unroll
        for (int j = 0; j < 4; ++j) {
            float bv = b1[n4 + j];
            #pragma unroll
            for (int i = 0; i < 4; ++i) acc[j][i] = bv;
        }
        for (int k = 0; k < K0DIM; ++k) {
            const float4 hv = *(const float4*)&h0t[k * RB + r4];
            const float4 wr = *(const float4*)&w1[(size_t)k * HDIM + n4];
            const float hva[4] = {hv.x, hv.y, hv.z, hv.w};
            const float wra[4] = {wr.x, wr.y, wr.z, wr.w};
            #pragma unroll
            for (int j = 0; j < 4; ++j)
                #pragma unroll
                for (int i = 0; i < 4; ++i)
                    acc[j][i] += hva[i] * wra[j];
        }
        #pragma unroll
        for (int j = 0; j < 4; ++j) {
            float4 o;
            o.x = fmaxf(acc[j][0], 0.f); o.y = fmaxf(acc[j][1], 0.f);
            o.z = fmaxf(acc[j][2], 0.f); o.w = fmaxf(acc[j][3], 0.f);
            *(float4*)&h1t[(n4 + j) * RB + r4] = o;
        }
    }
    __syncthreads();

    // ---- Phase C: z2 = h1 @ w2 + b2; q += relu(z2).w3; dz2 = (z2>0)?w3:0
    for (int it = 0; it < 2; ++it) {
        const int n4 = 4 * (ct + 32 * it);
        float acc[4][4];
        #pragma unroll
        for (int j = 0; j < 4; ++j) {
            float bv = b2[n4 + j];
            #pragma unroll
            for (int i = 0; i < 4; ++i) acc[j][i] = bv;
        }
        for (int k = 0; k < HDIM; ++k) {
            const float4 hv = *(const float4*)&h1t[k * RB + r4];
            const float4 wr = *(const float4*)&w2[(size_t)k * HDIM + n4];
            const float hva[4] = {hv.x, hv.y, hv.z, hv.w};
            const float wra[4] = {wr.x, wr.y, wr.z, wr.w};
            #pragma unroll
            for (int j = 0; j < 4; ++j)
                #pragma unroll
                for (int i = 0; i < 4; ++i)
                    acc[j][i] += hva[i] * wra[j];
        }
        float qp[4] = {0.f, 0.f, 0.f, 0.f};
        #pragma unroll
        for (int j = 0; j < 4; ++j) {
            float w3v = w3[n4 + j];
            float dz[4];
            #pragma unroll
            for (int i = 0; i < 4; ++i) {
                float z = acc[j][i];
                if (z > 0.f) { qp[i] += z * w3v; dz[i] = w3v; }
                else         { dz[i] = 0.f; }
            }
            float4 o; o.x = dz[0]; o.y = dz[1]; o.z = dz[2]; o.w = dz[3];
            *(float4*)&gt[(n4 + j) * RB + r4] = o;
        }
        #pragma unroll
        for (int i = 0; i < 4; ++i) atomicAdd(&qs[r4 + i], qp[i]);
    }
    __syncthreads();

    // ---- Phase D: dh1 = dz2 @ w2^T; dz1 = dh1 * (h1>0) -> overwrite h1t
    for (int it = 0; it < 2; ++it) {
        const int k4 = 4 * (ct + 32 * it);
        float acc[4][4];
        #pragma unroll
        for (int j = 0; j < 4; ++j)
            #pragma unroll
            for (int i = 0; i < 4; ++i) acc[j][i] = 0.f;
        for (int n = 0; n < HDIM; ++n) {
            const float4 gv = *(const float4*)&gt[n * RB + r4];
            const float4 wr = *(const float4*)&w2t[(size_t)n * HDIM + k4];
            const float gva[4] = {gv.x, gv.y, gv.z, gv.w};
            const float wra[4] = {wr.x, wr.y, wr.z, wr.w};
            #pragma unroll
            for (int j = 0; j < 4; ++j)
                #pragma unroll
                for (int i = 0; i < 4; ++i)
                    acc[j][i] += gva[i] * wra[j];
        }
        #pragma unroll
        for (int j = 0; j < 4; ++j) {
            float4 m = *(const float4*)&h1t[(k4 + j) * RB + r4];
            float4 o;
            o.x = (m.x > 0.f) ? acc[j][0] : 0.f;
            o.y = (m.y > 0.f) ? acc[j][1] : 0.f;
            o.z = (m.z > 0.f) ? acc[j][2] : 0.f;
            o.w = (m.w > 0.f) ? acc[j][3] : 0.f;
            *(float4*)&h1t[(k4 + j) * RB + r4] = o;   // own elements only
        }
    }
    __syncthreads();

    // ---- Phase E: score[r,d] = sum_k dz1T[k][r] * w1[64+d][k]; write q
    for (int idx = tid; idx < RB * DACT; idx += 256) {
        int r = idx >> 4, d = idx & 15;
        const float* wrow = &w1[(size_t)(DOBS + d) * HDIM];
        float s = 0.f;
        for (int k = 0; k < HDIM; ++k) s += h1t[k * RB + r] * wrow[k];
        score[(size_t)(row0 + r) * DACT + d] = s;
    }
    if (tid < RB) qout[row0 + tid] = qs[tid] + b3[0];
}

// ---------------------------------------------------------------------------
// SVGD update: one block per batch element b (N=32 particles, D=16).
__global__ __launch_bounds__(256) void svgd_kernel(
    const float* __restrict__ a_in,    // [BN,16]
    const float* __restrict__ score,   // [BN,16]
    const float* __restrict__ logp_in, // [BN] (ignored if first)
    float* __restrict__ logp_out,      // [BN]
    float* __restrict__ a_out,         // [BN,16]
    int first)
{
    __shared__ float X[32 * 16], S[32 * 16];
    __shared__ float D2[32 * 32], SB[1024], KM[32 * 32], P[32 * 32];
    const int b = blockIdx.x, tid = threadIdx.x;
    const size_t base = (size_t)b * 32 * 16;

    for (int idx = tid; idx < 512; idx += 256) {
        X[idx] = a_in[base + idx];
        S[idx] = score[base + idx];
    }
    __syncthreads();

    // pairwise squared distances
    for (int idx = tid; idx < 1024; idx += 256) {
        int i = idx >> 5, j = idx & 31;
        float s = 0.f;
        #pragma unroll
        for (int d = 0; d < 16; ++d) {
            float df = X[i * 16 + d] - X[j * 16 + d];
            s += df * df;
        }
        D2[idx] = s; SB[idx] = s;
    }
    __syncthreads();

    // bitonic sort of SB[1024] ascending (exact jnp.median semantics)
    for (int k = 2; k <= 1024; k <<= 1) {
        for (int j = k >> 1; j > 0; j >>= 1) {
            for (int idx = tid; idx < 1024; idx += 256) {
                int ixj = idx ^ j;
                if (ixj > idx) {
                    float x = SB[idx], y = SB[ixj];
                    bool up = ((idx & k) == 0);
                    if ((x > y) == up) { SB[idx] = y; SB[ixj] = x; }
                }
            }
            __syncthreads();
        }
    }

    const float med   = 0.5f * (SB[511] + SB[512]);
    const float gamma = 1.0f / (2.0f * (med / 3.4657359027997265f + 1e-8f));

    // K and P[i][j] = sum_d diff[i,j,d] * S[j,d]
    for (int idx = tid; idx < 1024; idx += 256) {
        int i = idx >> 5, j = idx & 31;
        KM[idx] = expf(-gamma * D2[idx]);
        float p = 0.f;
        #pragma unroll
        for (int d = 0; d < 16; ++d)
            p += (X[i * 16 + d] - X[j * 16 + d]) * S[j * 16 + d];
        P[idx] = p;
    }
    __syncthreads();

    // phi + particle update
    for (int idx = tid; idx < 512; idx += 256) {
        int i = idx >> 4, d = idx & 15;
        float s1 = 0.f, s2 = 0.f;
        #pragma unroll
        for (int j = 0; j < 32; ++j) {
            float kk = KM[i * 32 + j];
            s1 += kk * S[j * 16 + d];
            s2 += (X[i * 16 + d] - X[j * 16 + d]) * kk;
        }
        float phi = (s1 + 2.f * gamma * s2) * (1.f / 32.f);
        float av = X[idx] + 0.1f * phi;
        av = fminf(fmaxf(av, -1.f), 1.f);
        a_out[base + idx] = av;
    }

    // logp correction
    if (tid < 32) {
        int i = tid;
        float acc1 = 0.f, acc2 = 0.f;
        #pragma unroll
        for (int j = 0; j < 32; ++j) {
            float kk = KM[i * 32 + j];
            acc1 += kk * P[i * 32 + j];
            acc2 += (2.f * gamma * D2[i * 32 + j] - 16.f) * kk;
        }
        float tmp1 = -2.f * gamma * acc1 * (1.f / 32.f);
        float tmp2 = -2.f * gamma * acc2 * (1.f / 32.f);
        float prev = first ? 0.f : logp_in[b * 32 + i];
        logp_out[b * 32 + i] = prev - 0.1f * (tmp1 + tmp2);
    }
}

// ---------------------------------------------------------------------------
extern "C" void kernel_launch(void* const* d_in, const int* in_sizes, int n_in,
                              void* d_out, int out_size, void* d_ws, size_t ws_size,
                              hipStream_t stream) {
    const float* obs = (const float*)d_in[0];
    const float* a0  = (const float*)d_in[1];
    const float* w1  = (const float*)d_in[2];
    const float* b1  = (const float*)d_in[3];
    const float* w2  = (const float*)d_in[4];
    const float* b2  = (const float*)d_in[5];
    const float* w3  = (const float*)d_in[6];
    const float* b3  = (const float*)d_in[7];

    float* out_a    = (float*)d_out;                 // [BN,16]
    float* out_logp = out_a + (size_t)BNROWS * 16;   // [BN]
    float* out_q    = out_logp + BNROWS;             // [BN]

    float* ws    = (float*)d_ws;
    float* w2t   = ws;                                // 65536
    float* abuf0 = w2t + 65536;                       // BN*16
    float* abuf1 = abuf0 + (size_t)BNROWS * 16;       // BN*16
    float* scr   = abuf1 + (size_t)BNROWS * 16;       // BN*16
    float* logp  = scr + (size_t)BNROWS * 16;         // BN
    float* qtmp  = logp + BNROWS;                     // BN

    transpose_w2_kernel<<<256, 256, 0, stream>>>(w2, w2t);

    const int MB = BNROWS / RB;   // 4096 blocks

    // step 1
    mlp_kernel<<<MB, 256, 0, stream>>>(obs, a0, w1, b1, w2, b2, w3, b3, w2t, scr, qtmp);
    svgd_kernel<<<4096, 256, 0, stream>>>(a0, scr, nullptr, logp, abuf0, 1);
    // step 2
    mlp_kernel<<<MB, 256, 0, stream>>>(obs, abuf0, w1, b1, w2, b2, w3, b3, w2t, scr, qtmp);
    svgd_kernel<<<4096, 256, 0, stream>>>(abuf0, scr, logp, logp, abuf1, 0);
    // step 3 (q of this step is the q_vals output)
    mlp_kernel<<<MB, 256, 0, stream>>>(obs, abuf1, w1, b1, w2, b2, w3, b3, w2t, scr, out_q);
    svgd_kernel<<<4096, 256, 0, stream>>>(abuf1, scr, logp, out_logp, out_a, 0);
}

// Round 2
// 880.890 us; speedup vs baseline: 3.4105x; 3.4105x over previous
//
#include <hip/hip_runtime.h>
#include <hip/hip_bf16.h>
#include <math.h>

#define BNROWS (4096*32)   // 131072
#define RB     64          // rows per MLP block

typedef __attribute__((ext_vector_type(8))) short bf16x8;
typedef __attribute__((ext_vector_type(4))) float f32x4;

// ---------------------------------------------------------------------------
// One-time per launch: bf16 weight prep.
//   w1t  [256][96]  = w1^T, K padded 80->96 with zeros (B-operand of phase B)
//   w2bf [256][256] = w2 as-is, k-major                (B-operand of phase D)
//   w2tbf[256][256] = w2^T, n-major                    (B-operand of phase C)
//   w1abf[16][256]  = w1 rows 64..79 (action part)     (B-operand of phase E)
__global__ void prep_weights(const float* __restrict__ w1,
                             const float* __restrict__ w2,
                             __hip_bfloat16* __restrict__ w1t,
                             __hip_bfloat16* __restrict__ w2bf,
                             __hip_bfloat16* __restrict__ w2tbf,
                             __hip_bfloat16* __restrict__ w1abf) {
    int id = blockIdx.x * 256 + threadIdx.x;      // 65536 total
    int k = id >> 8, n = id & 255;
    float v2 = w2[id];
    w2bf[id] = __float2bfloat16(v2);
    w2tbf[n * 256 + k] = __float2bfloat16(v2);
    if (k < 80) {
        float v1 = w1[id];                        // w1[k][n], k<80
        w1t[n * 96 + k] = __float2bfloat16(v1);
        if (k >= 64) w1abf[(k - 64) * 256 + n] = __float2bfloat16(v1);
    } else if (k < 96) {
        w1t[n * 96 + k] = __float2bfloat16(0.f);
    }
}

// ---------------------------------------------------------------------------
// Fused critic forward + VJP wrt actions, bf16 MFMA (fp32 accumulate).
// 64 rows/block, 4 waves. Wave w owns col-tiles {4w..4w+3} x all 4 row-tiles,
// so each weight matrix is fetched exactly once per block.
// MFMA 16x16x32 bf16 layouts (verified m89/m91):
//   A[m=lane&15][k=(lane>>4)*8+j] ; B[k][n=lane&15] ; C/D col=lane&15,
//   row=(lane>>4)*4+reg.
__global__ __launch_bounds__(256) void mlp_mfma(
    const float* __restrict__ obs,   // [BN,64]
    const float* __restrict__ a_in,  // [BN,16]
    const float* __restrict__ b1,    // [256]
    const float* __restrict__ b2,    // [256]
    const float* __restrict__ w3,    // [256]
    const float* __restrict__ b3,    // [1]
    const __hip_bfloat16* __restrict__ w1t,    // [256][96]
    const __hip_bfloat16* __restrict__ w2bf,   // [256][256]
    const __hip_bfloat16* __restrict__ w2tbf,  // [256][256]
    const __hip_bfloat16* __restrict__ w1abf,  // [16][256]
    float* __restrict__ score,       // [BN,16]
    float* __restrict__ qout)        // [BN]
{
    // stride 264: words 132 ≡ 4 (mod 32) -> 2-way bank aliasing (free, m136)
    __shared__ __align__(16) __hip_bfloat16 bufA[RB * 264]; // h0t (stride 104) then dz2
    __shared__ __align__(16) __hip_bfloat16 bufB[RB * 264]; // h1 then dz1
    __shared__ float qpart[4][RB];

    const int tid  = threadIdx.x;
    const int row0 = blockIdx.x * RB;

    // ---- Phase A: stage h0 = [obs | a | 0pad] as bf16, [r][k] stride 104
    for (int idx = tid; idx < RB * 64; idx += 256) {
        int r = idx >> 6, k = idx & 63;
        bufA[r * 104 + k] = __float2bfloat16(obs[(size_t)(row0 + r) * 64 + k]);
    }
    for (int idx = tid; idx < RB * 16; idx += 256) {
        int r = idx >> 4, k = idx & 15;
        bufA[r * 104 + 64 + k] = __float2bfloat16(a_in[(size_t)(row0 + r) * 16 + k]);
        bufA[r * 104 + 80 + k] = __float2bfloat16(0.f);   // K pad 80..95
    }
    __syncthreads();

    const int lane = tid & 63;
    const int w    = tid >> 6;       // wave id -> col-tile group
    const int m    = lane & 15;
    const int q    = lane >> 4;
    const int qk   = q * 8;          // k offset inside a 32-chunk

    f32x4 acc[4][4];                 // [row-tile][col-tile]

    // ---- Phase B: z1 = h0 @ w1 + b1, relu -> bufB (h1, stride 264)
    #pragma unroll
    for (int tc = 0; tc < 4; ++tc) {
        float bv = b1[(w * 4 + tc) * 16 + m];
        #pragma unroll
        for (int rt = 0; rt < 4; ++rt) acc[rt][tc] = (f32x4){bv, bv, bv, bv};
    }
    for (int c = 0; c < 3; ++c) {
        bf16x8 af[4];
        #pragma unroll
        for (int rt = 0; rt < 4; ++rt)
            af[rt] = *(const bf16x8*)&bufA[(rt * 16 + m) * 104 + c * 32 + qk];
        #pragma unroll
        for (int tc = 0; tc < 4; ++tc) {
            bf16x8 bf = *(const bf16x8*)&w1t[((w * 4 + tc) * 16 + m) * 96 + c * 32 + qk];
            #pragma unroll
            for (int rt = 0; rt < 4; ++rt)
                acc[rt][tc] = __builtin_amdgcn_mfma_f32_16x16x32_bf16(af[rt], bf, acc[rt][tc], 0, 0, 0);
        }
    }
    #pragma unroll
    for (int rt = 0; rt < 4; ++rt)
        #pragma unroll
        for (int tc = 0; tc < 4; ++tc)
            #pragma unroll
            for (int i = 0; i < 4; ++i) {
                float z = acc[rt][tc][i];
                bufB[(rt * 16 + q * 4 + i) * 264 + (w * 4 + tc) * 16 + m] =
                    __float2bfloat16(fmaxf(z, 0.f));
            }
    __syncthreads();

    // ---- Phase C: z2 = h1 @ w2 + b2 ; q = sum relu(z2)*w3 ; dz2 -> bufA
    #pragma unroll
    for (int tc = 0; tc < 4; ++tc) {
        float bv = b2[(w * 4 + tc) * 16 + m];
        #pragma unroll
        for (int rt = 0; rt < 4; ++rt) acc[rt][tc] = (f32x4){bv, bv, bv, bv};
    }
    for (int c = 0; c < 8; ++c) {
        bf16x8 af[4];
        #pragma unroll
        for (int rt = 0; rt < 4; ++rt)
            af[rt] = *(const bf16x8*)&bufB[(rt * 16 + m) * 264 + c * 32 + qk];
        #pragma unroll
        for (int tc = 0; tc < 4; ++tc) {
            bf16x8 bf = *(const bf16x8*)&w2tbf[((w * 4 + tc) * 16 + m) * 256 + c * 32 + qk];
            #pragma unroll
            for (int rt = 0; rt < 4; ++rt)
                acc[rt][tc] = __builtin_amdgcn_mfma_f32_16x16x32_bf16(af[rt], bf, acc[rt][tc], 0, 0, 0);
        }
    }
    {
        float qp[4][4] = {};         // [rt][i]
        #pragma unroll
        for (int tc = 0; tc < 4; ++tc) {
            float w3v = w3[(w * 4 + tc) * 16 + m];
            #pragma unroll
            for (int rt = 0; rt < 4; ++rt)
                #pragma unroll
                for (int i = 0; i < 4; ++i) {
                    float z = acc[rt][tc][i];
                    float dz;
                    if (z > 0.f) { qp[rt][i] += z * w3v; dz = w3v; }
                    else         { dz = 0.f; }
                    bufA[(rt * 16 + q * 4 + i) * 264 + (w * 4 + tc) * 16 + m] =
                        __float2bfloat16(dz);
                }
        }
        #pragma unroll
        for (int rt = 0; rt < 4; ++rt)
            #pragma unroll
            for (int i = 0; i < 4; ++i) {
                float v = qp[rt][i];
                v += __shfl_xor(v, 1); v += __shfl_xor(v, 2);
                v += __shfl_xor(v, 4); v += __shfl_xor(v, 8);
                if (m == 0) qpart[w][rt * 16 + q * 4 + i] = v;
            }
    }
    __syncthreads();

    // ---- q write + Phase D: dh1 = dz2 @ w2^T ; dz1 = dh1*(h1>0) -> bufB
    if (tid < RB)
        qout[row0 + tid] = qpart[0][tid] + qpart[1][tid] + qpart[2][tid] +
                           qpart[3][tid] + b3[0];

    #pragma unroll
    for (int tc = 0; tc < 4; ++tc)
        #pragma unroll
        for (int rt = 0; rt < 4; ++rt) acc[rt][tc] = (f32x4){0.f, 0.f, 0.f, 0.f};
    for (int c = 0; c < 8; ++c) {
        bf16x8 af[4];
        #pragma unroll
        for (int rt = 0; rt < 4; ++rt)
            af[rt] = *(const bf16x8*)&bufA[(rt * 16 + m) * 264 + c * 32 + qk];
        #pragma unroll
        for (int tc = 0; tc < 4; ++tc) {
            bf16x8 bf = *(const bf16x8*)&w2bf[((w * 4 + tc) * 16 + m) * 256 + c * 32 + qk];
            #pragma unroll
            for (int rt = 0; rt < 4; ++rt)
                acc[rt][tc] = __builtin_amdgcn_mfma_f32_16x16x32_bf16(af[rt], bf, acc[rt][tc], 0, 0, 0);
        }
    }
    #pragma unroll
    for (int rt = 0; rt < 4; ++rt)
        #pragma unroll
        for (int tc = 0; tc < 4; ++tc)
            #pragma unroll
            for (int i = 0; i < 4; ++i) {
                int r = rt * 16 + q * 4 + i, n = (w * 4 + tc) * 16 + m;
                float h = __bfloat162float(bufB[r * 264 + n]);
                float dz = (h > 0.f) ? acc[rt][tc][i] : 0.f;
                bufB[r * 264 + n] = __float2bfloat16(dz);
            }
    __syncthreads();

    // ---- Phase E: score = dz1 @ w1[64:80]^T  (wave w -> row-tile w)
    {
        f32x4 acc2 = (f32x4){0.f, 0.f, 0.f, 0.f};
        for (int c = 0; c < 8; ++c) {
            bf16x8 af = *(const bf16x8*)&bufB[(w * 16 + m) * 264 + c * 32 + qk];
            bf16x8 bf = *(const bf16x8*)&w1abf[m * 256 + c * 32 + qk];
            acc2 = __builtin_amdgcn_mfma_f32_16x16x32_bf16(af, bf, acc2, 0, 0, 0);
        }
        #pragma unroll
        for (int i = 0; i < 4; ++i)
            score[(size_t)(row0 + w * 16 + q * 4 + i) * 16 + m] = acc2[i];
    }
}

// ---------------------------------------------------------------------------
// SVGD update: one block per batch element b (N=32 particles, D=16).
__global__ __launch_bounds__(256) void svgd_kernel(
    const float* __restrict__ a_in,    // [BN,16]
    const float* __restrict__ score,   // [BN,16]
    const float* __restrict__ logp_in, // [BN] (ignored if first)
    float* __restrict__ logp_out,      // [BN]
    float* __restrict__ a_out,         // [BN,16]
    int first)
{
    __shared__ float X[32 * 16], S[32 * 16];
    __shared__ float D2[32 * 32], SB[1024], KM[32 * 32], P[32 * 32];
    const int b = blockIdx.x, tid = threadIdx.x;
    const size_t base = (size_t)b * 32 * 16;

    for (int idx = tid; idx < 512; idx += 256) {
        X[idx] = a_in[base + idx];
        S[idx] = score[base + idx];
    }
    __syncthreads();

    for (int idx = tid; idx < 1024; idx += 256) {
        int i = idx >> 5, j = idx & 31;
        float s = 0.f;
        #pragma unroll
        for (int d = 0; d < 16; ++d) {
            float df = X[i * 16 + d] - X[j * 16 + d];
            s += df * df;
        }
        D2[idx] = s; SB[idx] = s;
    }
    __syncthreads();

    // bitonic sort of SB[1024] ascending (exact jnp.median semantics)
    for (int k = 2; k <= 1024; k <<= 1) {
        for (int j = k >> 1; j > 0; j >>= 1) {
            for (int idx = tid; idx < 1024; idx += 256) {
                int ixj = idx ^ j;
                if (ixj > idx) {
                    float x = SB[idx], y = SB[ixj];
                    bool up = ((idx & k) == 0);
                    if ((x > y) == up) { SB[idx] = y; SB[ixj] = x; }
                }
            }
            __syncthreads();
        }
    }

    const float med   = 0.5f * (SB[511] + SB[512]);
    const float gamma = 1.0f / (2.0f * (med / 3.4657359027997265f + 1e-8f));

    for (int idx = tid; idx < 1024; idx += 256) {
        int i = idx >> 5, j = idx & 31;
        KM[idx] = expf(-gamma * D2[idx]);
        float p = 0.f;
        #pragma unroll
        for (int d = 0; d < 16; ++d)
            p += (X[i * 16 + d] - X[j * 16 + d]) * S[j * 16 + d];
        P[idx] = p;
    }
    __syncthreads();

    for (int idx = tid; idx < 512; idx += 256) {
        int i = idx >> 4, d = idx & 15;
        float s1 = 0.f, s2 = 0.f;
        #pragma unroll
        for (int j = 0; j < 32; ++j) {
            float kk = KM[i * 32 + j];
            s1 += kk * S[j * 16 + d];
            s2 += (X[i * 16 + d] - X[j * 16 + d]) * kk;
        }
        float phi = (s1 + 2.f * gamma * s2) * (1.f / 32.f);
        float av = X[idx] + 0.1f * phi;
        av = fminf(fmaxf(av, -1.f), 1.f);
        a_out[base + idx] = av;
    }

    if (tid < 32) {
        int i = tid;
        float acc1 = 0.f, acc2 = 0.f;
        #pragma unroll
        for (int j = 0; j < 32; ++j) {
            float kk = KM[i * 32 + j];
            acc1 += kk * P[i * 32 + j];
            acc2 += (2.f * gamma * D2[i * 32 + j] - 16.f) * kk;
        }
        float tmp1 = -2.f * gamma * acc1 * (1.f / 32.f);
        float tmp2 = -2.f * gamma * acc2 * (1.f / 32.f);
        float prev = first ? 0.f : logp_in[b * 32 + i];
        logp_out[b * 32 + i] = prev - 0.1f * (tmp1 + tmp2);
    }
}

// ---------------------------------------------------------------------------
extern "C" void kernel_launch(void* const* d_in, const int* in_sizes, int n_in,
                              void* d_out, int out_size, void* d_ws, size_t ws_size,
                              hipStream_t stream) {
    const float* obs = (const float*)d_in[0];
    const float* a0  = (const float*)d_in[1];
    const float* w1  = (const float*)d_in[2];
    const float* b1  = (const float*)d_in[3];
    const float* w2  = (const float*)d_in[4];
    const float* b2  = (const float*)d_in[5];
    const float* w3  = (const float*)d_in[6];
    const float* b3  = (const float*)d_in[7];

    float* out_a    = (float*)d_out;                 // [BN,16]
    float* out_logp = out_a + (size_t)BNROWS * 16;   // [BN]
    float* out_q    = out_logp + BNROWS;             // [BN]

    char* p = (char*)d_ws;
    __hip_bfloat16* w1t   = (__hip_bfloat16*)p; p += 256 * 96 * 2;
    __hip_bfloat16* w2bf  = (__hip_bfloat16*)p; p += 256 * 256 * 2;
    __hip_bfloat16* w2tbf = (__hip_bfloat16*)p; p += 256 * 256 * 2;
    __hip_bfloat16* w1abf = (__hip_bfloat16*)p; p += 16 * 256 * 2;
    float* abuf0 = (float*)p; p += (size_t)BNROWS * 16 * 4;
    float* abuf1 = (float*)p; p += (size_t)BNROWS * 16 * 4;
    float* scr   = (float*)p; p += (size_t)BNROWS * 16 * 4;
    float* logp  = (float*)p; p += (size_t)BNROWS * 4;
    float* qtmp  = (float*)p;

    prep_weights<<<256, 256, 0, stream>>>(w1, w2, w1t, w2bf, w2tbf, w1abf);

    const int MB = BNROWS / RB;   // 2048 blocks

    // step 1
    mlp_mfma<<<MB, 256, 0, stream>>>(obs, a0, b1, b2, w3, b3,
                                     w1t, w2bf, w2tbf, w1abf, scr, qtmp);
    svgd_kernel<<<4096, 256, 0, stream>>>(a0, scr, nullptr, logp, abuf0, 1);
    // step 2
    mlp_mfma<<<MB, 256, 0, stream>>>(obs, abuf0, b1, b2, w3, b3,
                                     w1t, w2bf, w2tbf, w1abf, scr, qtmp);
    svgd_kernel<<<4096, 256, 0, stream>>>(abuf0, scr, logp, logp, abuf1, 0);
    // step 3 (q of this step is the q_vals output)
    mlp_mfma<<<MB, 256, 0, stream>>>(obs, abuf1, b1, b2, w3, b3,
                                     w1t, w2bf, w2tbf, w1abf, scr, out_q);
    svgd_kernel<<<4096, 256, 0, stream>>>(abuf1, scr, logp, out_logp, out_a, 0);
}